// Round 1
// baseline (59716.748 us; speedup 1.0000x reference)
//
#include <hip/hip_runtime.h>
#include <math.h>

// PGJANET: B=128, T=1024, H=256, OUT=2. Sequential scan -> persistent kernel.
// Partition: 16 batch-groups (MB=8 batches) x 32 col-slices (NS=8 h-cols) = 512 WGs.
// Per step: stage1 (a,p1,p2 -> u) ; group barrier ; stage2 (z,hcand -> h_new) ; group barrier.
// Weights LDS-resident (59KB/WG -> 2 WG/CU, all 512 co-resident).

#define B_   128
#define T_   1024
#define H_   256
#define GB   16    // batch groups
#define GC   32    // col slices per group
#define MB   8     // batches per group
#define NS   8     // h-cols per WG
#define NTHR 256

__launch_bounds__(NTHR, 2)
__global__ void pgjanet_persist(
    const float* __restrict__ x,   const float* __restrict__ h0,
    const float* __restrict__ Wa,  const float* __restrict__ ba,
    const float* __restrict__ Wp1, const float* __restrict__ bp1,
    const float* __restrict__ Wp2, const float* __restrict__ bp2,
    const float* __restrict__ Wz,  const float* __restrict__ bz,
    const float* __restrict__ Wh,  const float* __restrict__ bh,
    const float* __restrict__ Wo,  const float* __restrict__ bo,
    float* __restrict__ out,            // [B*T*2] then h_n [B*H]
    float* __restrict__ u_glob,         // [B*H]
    float* __restrict__ h_glob,         // [2][B*H]
    unsigned* __restrict__ ctrs)        // [512] uints: c1 at g*16, c2 at 256+g*16
{
  // LDS: weights transposed to [col][k] so k-chunk reads are contiguous b128,
  // broadcast across the 8 batch-lanes sharing a k-chunk (conflict-free).
  __shared__ __align__(16) float w1t[3 * NS * 256];  // rows 1..256 of Wa/Wp1/Wp2, 24KB
  __shared__ __align__(16) float w2t[2 * NS * 512];  // Wz,Wh cols, 32KB
  __shared__ float s1res[3 * NS * MB];
  __shared__ float s2res[2 * NS * MB];
  __shared__ float w1r0[3 * NS], b1l[3 * NS];
  __shared__ float bzl[NS], bhl[NS], wol[NS * 2];
  __shared__ float xin[MB * 4];  // amp, cos(ph), sin(ph) per batch

  const int wg   = blockIdx.x;
  const int g    = wg >> 5;        // / GC
  const int gc   = wg & (GC - 1);  // % GC
  const int tid  = threadIdx.x;
  const int lane = tid & 63;
  const int wave = tid >> 6;
  const int b    = lane >> 3;      // batch within group (0..7)
  const int ks   = lane & 7;       // k-chunk lane (0..7), 4 floats each
  const int b0   = g * MB;

  // ---- one-time: stage weights into LDS (transposed) ----
  for (int i = tid; i < 3 * NS * 256; i += NTHR) {
    int c = i >> 8, k = i & 255;
    int mat = c >> 3, n = c & 7;
    const float* W = (mat == 0) ? Wa : (mat == 1 ? Wp1 : Wp2);
    w1t[i] = W[(1 + k) * H_ + gc * NS + n];
  }
  for (int i = tid; i < 2 * NS * 512; i += NTHR) {
    int c = i >> 9, k = i & 511;
    const float* W = (c < NS) ? Wz : Wh;
    int n = c & 7;
    w2t[i] = W[k * H_ + gc * NS + n];
  }
  if (tid < 3 * NS) {
    int mat = tid >> 3, n = tid & 7;
    const float* W  = (mat == 0) ? Wa : (mat == 1 ? Wp1 : Wp2);
    const float* bb = (mat == 0) ? ba : (mat == 1 ? bp1 : bp2);
    w1r0[tid] = W[gc * NS + n];
    b1l[tid]  = bb[gc * NS + n];
  }
  if (tid < NS)     { bzl[tid] = bz[gc * NS + tid]; bhl[tid] = bh[gc * NS + tid]; }
  if (tid < 2 * NS) { wol[tid] = Wo[(gc * NS + (tid >> 1)) * 2 + (tid & 1)]; }
  __syncthreads();

  unsigned* c1 = ctrs + g * 16;
  unsigned* c2 = ctrs + 256 + g * 16;

  for (int t = 0; t < T_; ++t) {
    // ---- wait for h(t) from previous step (group-local barrier on c2) ----
    if (tid == 0 && t > 0) {
      const unsigned tgt = (unsigned)(GC * t);
      while (__hip_atomic_load(c2, __ATOMIC_RELAXED, __HIP_MEMORY_SCOPE_AGENT) < tgt)
        __builtin_amdgcn_s_sleep(1);
      (void)__hip_atomic_load(c2, __ATOMIC_ACQUIRE, __HIP_MEMORY_SCOPE_AGENT); // inv caches
    }
    __syncthreads();

    const float* hsrc = (t == 0) ? (h0 + b0 * H_)
                                 : (h_glob + (t & 1) * (B_ * H_) + b0 * H_);

    if (tid < MB) {
      float amp = x[(b0 + tid) * (T_ * 2) + t * 2 + 0];
      float ph  = x[(b0 + tid) * (T_ * 2) + t * 2 + 1];
      xin[tid * 4 + 0] = amp;
      xin[tid * 4 + 1] = cosf(ph);
      xin[tid * 4 + 2] = sinf(ph);
    }

    // h(t) chunks for this lane's batch, straight into registers (reused in stage2)
    float4 hv[8];
#pragma unroll
    for (int kt = 0; kt < 8; ++kt)
      hv[kt] = *(const float4*)(hsrc + b * H_ + kt * 32 + ks * 4);

    // ---- stage1: pre-activations of a,p1,p2 (h-part); 6 cols per wave ----
    float acc[6] = {0.f, 0.f, 0.f, 0.f, 0.f, 0.f};
    const int cb1 = wave * 6;
#pragma unroll
    for (int kt = 0; kt < 8; ++kt) {
      float4 h4 = hv[kt];
#pragma unroll
      for (int c = 0; c < 6; ++c) {
        float4 w4 = *(const float4*)(w1t + (cb1 + c) * 256 + kt * 32 + ks * 4);
        acc[c] = fmaf(h4.x, w4.x, acc[c]);
        acc[c] = fmaf(h4.y, w4.y, acc[c]);
        acc[c] = fmaf(h4.z, w4.z, acc[c]);
        acc[c] = fmaf(h4.w, w4.w, acc[c]);
      }
    }
#pragma unroll
    for (int c = 0; c < 6; ++c) {
      float v = acc[c];
      v += __shfl_xor(v, 1);
      v += __shfl_xor(v, 2);
      v += __shfl_xor(v, 4);
      if (ks == 0) s1res[(cb1 + c) * MB + b] = v;
    }
    __syncthreads();

    // ---- epilogue1: u = a*p1*p2*(1-a)*(1-p1)*(1-p2), publish u slice ----
    if (tid < MB * NS) {
      int eb = tid >> 3, n = tid & 7;
      float ap  = s1res[(0 * NS + n) * MB + eb] + xin[eb * 4 + 0] * w1r0[0 * NS + n] + b1l[0 * NS + n];
      float p1p = s1res[(1 * NS + n) * MB + eb] + xin[eb * 4 + 1] * w1r0[1 * NS + n] + b1l[1 * NS + n];
      float p2p = s1res[(2 * NS + n) * MB + eb] + xin[eb * 4 + 2] * w1r0[2 * NS + n] + b1l[2 * NS + n];
      float a  = tanhf(ap), p1 = tanhf(p1p), p2 = tanhf(p2p);
      float u  = a * p1 * p2 * (1.f - a) * (1.f - p1) * (1.f - p2);
      u_glob[(b0 + eb) * H_ + gc * NS + n] = u;
    }
    __syncthreads();  // drains u stores (waitcnt before barrier)
    if (tid == 0) {
      __threadfence();  // push dirty L2 -> coherence point
      __hip_atomic_fetch_add(c1, 1u, __ATOMIC_RELEASE, __HIP_MEMORY_SCOPE_AGENT);
      const unsigned tgt = (unsigned)(GC * (t + 1));
      while (__hip_atomic_load(c1, __ATOMIC_RELAXED, __HIP_MEMORY_SCOPE_AGENT) < tgt)
        __builtin_amdgcn_s_sleep(1);
      (void)__hip_atomic_load(c1, __ATOMIC_ACQUIRE, __HIP_MEMORY_SCOPE_AGENT);
    }
    __syncthreads();

    // ---- stage2: z, h_cand; K=512 = [u(256), h(256)]; 4 (z,hc)-pairs per wave ----
    float4 uv[8];
#pragma unroll
    for (int kt = 0; kt < 8; ++kt)
      uv[kt] = *(const float4*)(u_glob + (b0 + b) * H_ + kt * 32 + ks * 4);

    float acc2[4] = {0.f, 0.f, 0.f, 0.f};
    const int cb2 = wave * 4;
#pragma unroll
    for (int kt = 0; kt < 16; ++kt) {
      float4 h4 = (kt < 8) ? uv[kt] : hv[kt - 8];
#pragma unroll
      for (int c = 0; c < 4; ++c) {
        float4 w4 = *(const float4*)(w2t + (cb2 + c) * 512 + kt * 32 + ks * 4);
        acc2[c] = fmaf(h4.x, w4.x, acc2[c]);
        acc2[c] = fmaf(h4.y, w4.y, acc2[c]);
        acc2[c] = fmaf(h4.z, w4.z, acc2[c]);
        acc2[c] = fmaf(h4.w, w4.w, acc2[c]);
      }
    }
#pragma unroll
    for (int c = 0; c < 4; ++c) {
      float v = acc2[c];
      v += __shfl_xor(v, 1);
      v += __shfl_xor(v, 2);
      v += __shfl_xor(v, 4);
      if (ks == 0) s2res[(cb2 + c) * MB + b] = v;
    }
    __syncthreads();

    // ---- epilogue2: h_new, publish h slice, fused out += h_new @ Wo ----
    if (tid < MB * NS) {
      int eb = tid >> 3, m = tid & 7;
      float zp = s2res[m * MB + eb] + bzl[m];
      float hp = s2res[(NS + m) * MB + eb] + bhl[m];
      float z  = 1.f / (1.f + expf(-zp));
      float hc = tanhf(hp);
      float hprev = hsrc[eb * H_ + gc * NS + m];
      float hn = z * hprev + (1.f - z) * hc;
      h_glob[((t + 1) & 1) * (B_ * H_) + (b0 + eb) * H_ + gc * NS + m] = hn;
      if (t == T_ - 1)
        out[B_ * T_ * 2 + (b0 + eb) * H_ + gc * NS + m] = hn;  // h_n
      float v0 = hn * wol[m * 2 + 0];
      float v1 = hn * wol[m * 2 + 1];
      v0 += __shfl_xor(v0, 1); v1 += __shfl_xor(v1, 1);
      v0 += __shfl_xor(v0, 2); v1 += __shfl_xor(v1, 2);
      v0 += __shfl_xor(v0, 4); v1 += __shfl_xor(v1, 4);
      if (m == 0) {
        if (gc == 0) { v0 += bo[0]; v1 += bo[1]; }
        atomicAdd(&out[((b0 + eb) * T_ + t) * 2 + 0], v0);
        atomicAdd(&out[((b0 + eb) * T_ + t) * 2 + 1], v1);
      }
    }
    __syncthreads();  // drains h stores
    if (tid == 0) {
      __threadfence();
      __hip_atomic_fetch_add(c2, 1u, __ATOMIC_RELEASE, __HIP_MEMORY_SCOPE_AGENT);
    }
  }
}

extern "C" void kernel_launch(void* const* d_in, const int* in_sizes, int n_in,
                              void* d_out, int out_size, void* d_ws, size_t ws_size,
                              hipStream_t stream) {
  (void)in_sizes; (void)n_in; (void)out_size; (void)ws_size;
  const float* x   = (const float*)d_in[0];
  const float* h0  = (const float*)d_in[1];
  const float* Wa  = (const float*)d_in[2];
  const float* ba  = (const float*)d_in[3];
  const float* Wp1 = (const float*)d_in[4];
  const float* bp1 = (const float*)d_in[5];
  const float* Wp2 = (const float*)d_in[6];
  const float* bp2 = (const float*)d_in[7];
  const float* Wz  = (const float*)d_in[8];
  const float* bz  = (const float*)d_in[9];
  const float* Wh  = (const float*)d_in[10];
  const float* bh  = (const float*)d_in[11];
  const float* Wo  = (const float*)d_in[12];
  const float* bo  = (const float*)d_in[13];

  float* out = (float*)d_out;
  char*  ws  = (char*)d_ws;
  float*    u_glob = (float*)ws;                           // 128*256*4 = 131072 B
  float*    h_glob = (float*)(ws + 131072);                // 2*128*256*4 = 262144 B
  unsigned* ctrs   = (unsigned*)(ws + 131072 + 262144);    // 2048 B of flags

  // out region accumulated via atomics -> zero it; flags must start at 0 each replay.
  hipMemsetAsync(out, 0, (size_t)B_ * T_ * 2 * sizeof(float), stream);
  hipMemsetAsync(ctrs, 0, 2048, stream);

  pgjanet_persist<<<dim3(GB * GC), dim3(NTHR), 0, stream>>>(
      x, h0, Wa, ba, Wp1, bp1, Wp2, bp2, Wz, bz, Wh, bh, Wo, bo,
      out, u_glob, h_glob, ctrs);
}

// Round 2
// 20362.654 us; speedup vs baseline: 2.9327x; 2.9327x over previous
//
#include <hip/hip_runtime.h>
#include <math.h>

// PGJANET: B=128, T=1024, H=256, OUT=2. Persistent kernel, 16 batch-groups x 32
// col-slice WGs. Cross-WG exchange via system-scope (sc0 sc1) cache-bypassing
// loads/stores to Infinity Cache -- NO L2 writeback/invalidate anywhere.

#define B_   128
#define T_   1024
#define H_   256
#define GB   16    // batch groups
#define GC   32    // col-slice WGs per group
#define MB   8     // batches per group
#define NS   8     // h-cols per WG
#define NTHR 256
#define HPAD 264   // padded LDS row stride (floats) for h/u staging

typedef float f32x4 __attribute__((ext_vector_type(4)));

// --- system-scope (coherence-point) memory ops: bypass L1+L2, no cache maint ---
__device__ __forceinline__ void sys_ld2_x4(const float* p0, const float* p1,
                                           f32x4& a, f32x4& b) {
  asm volatile("global_load_dwordx4 %0, %2, off sc0 sc1\n\t"
               "global_load_dwordx4 %1, %3, off sc0 sc1\n\t"
               "s_waitcnt vmcnt(0)"
               : "=v"(a), "=v"(b) : "v"(p0), "v"(p1) : "memory");
}
__device__ __forceinline__ void sys_st_f32(float* p, float v) {
  asm volatile("global_store_dword %0, %1, off sc0 sc1" :: "v"(p), "v"(v) : "memory");
}
__device__ __forceinline__ void sys_st_flag(unsigned* p, unsigned v) {
  // drain this thread's outstanding stores first (release-without-wbl2)
  asm volatile("s_waitcnt vmcnt(0)\n\t"
               "global_store_dword %0, %1, off sc0 sc1" :: "v"(p), "v"(v) : "memory");
}
__device__ __forceinline__ unsigned sys_ld_u32(const unsigned* p) {
  unsigned v;
  asm volatile("global_load_dword %0, %1, off sc0 sc1\n\ts_waitcnt vmcnt(0)"
               : "=v"(v) : "v"(p) : "memory");
  return v;
}
__device__ __forceinline__ void vm_drain() {
  asm volatile("s_waitcnt vmcnt(0)" ::: "memory");
}

// all 64 lanes of every wave poll the group's 32 per-WG flags (one coalesced
// 128B load) until all reach tgt. Lanes >=32 auto-pass.
__device__ __forceinline__ void wait_flags(const unsigned* fl, unsigned tgt, int lane) {
  const unsigned* p = fl + (lane & 31);
  for (;;) {
    unsigned v = tgt;
    if (lane < 32) v = sys_ld_u32(p);
    if (__ballot(v >= tgt) == ~0ull) return;
    __builtin_amdgcn_s_sleep(1);
  }
}

__launch_bounds__(NTHR, 2)
__global__ void pgjanet_persist(
    const float* __restrict__ x,   const float* __restrict__ h0,
    const float* __restrict__ Wa,  const float* __restrict__ ba,
    const float* __restrict__ Wp1, const float* __restrict__ bp1,
    const float* __restrict__ Wp2, const float* __restrict__ bp2,
    const float* __restrict__ Wz,  const float* __restrict__ bz,
    const float* __restrict__ Wh,  const float* __restrict__ bh,
    const float* __restrict__ Wo,  const float* __restrict__ bo,
    float* __restrict__ out,            // [B*T*2] then h_n [B*H]
    float* __restrict__ u_glob,         // [B*H]
    float* __restrict__ h_glob,         // [B*H]
    unsigned* __restrict__ ctrs)        // flags1[16][32], flags2[16][32]
{
  __shared__ __align__(16) float w1t[3 * NS * 256];   // 24 KB
  __shared__ __align__(16) float w2t[2 * NS * 512];   // 32 KB
  __shared__ __align__(16) float h_lds[MB * HPAD];    // 8.25 KB (padded)
  __shared__ __align__(16) float u_lds[MB * HPAD];    // 8.25 KB
  __shared__ float s1res[3 * NS * MB];
  __shared__ float s2res[2 * NS * MB];
  __shared__ float w1r0[3 * NS], b1l[3 * NS];
  __shared__ float bzl[NS], bhl[NS];
  __shared__ float wo_s[H_ * 2];                      // full Wo for gc0 out-row
  __shared__ float xin[MB * 4];

  const int wg   = blockIdx.x;
  const int g    = wg >> 5;
  const int gc   = wg & (GC - 1);
  const int tid  = threadIdx.x;
  const int lane = tid & 63;
  const int wave = tid >> 6;
  const int b    = lane >> 3;
  const int ks   = lane & 7;
  const int b0   = g * MB;

  // ---- one-time weight staging (transposed to [col][k]) ----
  for (int i = tid; i < 3 * NS * 256; i += NTHR) {
    int c = i >> 8, k = i & 255;
    int mat = c >> 3, n = c & 7;
    const float* W = (mat == 0) ? Wa : (mat == 1 ? Wp1 : Wp2);
    w1t[i] = W[(1 + k) * H_ + gc * NS + n];
  }
  for (int i = tid; i < 2 * NS * 512; i += NTHR) {
    int c = i >> 9, k = i & 511;
    const float* W = (c < NS) ? Wz : Wh;
    int n = c & 7;
    w2t[i] = W[k * H_ + gc * NS + n];
  }
  if (tid < 3 * NS) {
    int mat = tid >> 3, n = tid & 7;
    const float* W  = (mat == 0) ? Wa : (mat == 1 ? Wp1 : Wp2);
    const float* bb = (mat == 0) ? ba : (mat == 1 ? bp1 : bp2);
    w1r0[tid] = W[gc * NS + n];
    b1l[tid]  = bb[gc * NS + n];
  }
  if (tid < NS) { bzl[tid] = bz[gc * NS + tid]; bhl[tid] = bh[gc * NS + tid]; }
  if (gc == 0) for (int i = tid; i < H_ * 2; i += NTHR) wo_s[i] = Wo[i];
  const float bo0 = bo[0], bo1 = bo[1];
  __syncthreads();

  unsigned* flags1 = ctrs + g * GC;
  unsigned* flags2 = ctrs + GB * GC + g * GC;
  const float* grp_h = h_glob + b0 * H_;
  const float* grp_u = u_glob + b0 * H_;

  for (int t = 0; t < T_; ++t) {
    // ---- wait for h(t); stage into LDS ----
    if (t > 0) wait_flags(flags2, (unsigned)t, lane);
    const float* hsrc = (t == 0) ? (h0 + b0 * H_) : grp_h;
    {
      f32x4 ha, hb;
      sys_ld2_x4(hsrc + tid * 4, hsrc + tid * 4 + 1024, ha, hb);
      int i0 = tid, i1 = tid + 256;
      *(f32x4*)(h_lds + (i0 >> 6) * HPAD + (i0 & 63) * 4) = ha;
      *(f32x4*)(h_lds + (i1 >> 6) * HPAD + (i1 & 63) * 4) = hb;
    }
    if (tid < MB) {
      float2 xt = *(const float2*)(x + (b0 + tid) * (T_ * 2) + t * 2);
      xin[tid * 4 + 0] = xt.x;
      xin[tid * 4 + 1] = cosf(xt.y);
      xin[tid * 4 + 2] = sinf(xt.y);
    }
    __syncthreads();                               // B1: h_lds/xin ready

    // ---- fused out-row t-1 (gc0 only; h_lds holds hs[t-1]) ----
    if (gc == 0 && t > 0) {
      int ob = tid >> 5, oc = tid & 31;
      const float* hr = h_lds + ob * HPAD + oc * 8;
      float v0 = 0.f, v1 = 0.f;
#pragma unroll
      for (int j = 0; j < 8; ++j) {
        float hh = hr[j];
        v0 = fmaf(hh, wo_s[(oc * 8 + j) * 2 + 0], v0);
        v1 = fmaf(hh, wo_s[(oc * 8 + j) * 2 + 1], v1);
      }
      v0 += __shfl_xor(v0, 1);  v1 += __shfl_xor(v1, 1);
      v0 += __shfl_xor(v0, 2);  v1 += __shfl_xor(v1, 2);
      v0 += __shfl_xor(v0, 4);  v1 += __shfl_xor(v1, 4);
      v0 += __shfl_xor(v0, 8);  v1 += __shfl_xor(v1, 8);
      v0 += __shfl_xor(v0, 16); v1 += __shfl_xor(v1, 16);
      if (oc == 0) {
        out[((b0 + ob) * T_ + (t - 1)) * 2 + 0] = v0 + bo0;
        out[((b0 + ob) * T_ + (t - 1)) * 2 + 1] = v1 + bo1;
      }
    }

    // ---- stage1: h-part of a,p1,p2 pre-acts (6 cols/wave) ----
    f32x4 hv[8];
#pragma unroll
    for (int kt = 0; kt < 8; ++kt)
      hv[kt] = *(const f32x4*)(h_lds + b * HPAD + kt * 32 + ks * 4);

    float acc[6] = {0.f, 0.f, 0.f, 0.f, 0.f, 0.f};
    const int cb1 = wave * 6;
#pragma unroll
    for (int kt = 0; kt < 8; ++kt) {
      f32x4 h4 = hv[kt];
#pragma unroll
      for (int c = 0; c < 6; ++c) {
        f32x4 w4 = *(const f32x4*)(w1t + (cb1 + c) * 256 + kt * 32 + ks * 4);
        acc[c] = fmaf(h4[0], w4[0], acc[c]);
        acc[c] = fmaf(h4[1], w4[1], acc[c]);
        acc[c] = fmaf(h4[2], w4[2], acc[c]);
        acc[c] = fmaf(h4[3], w4[3], acc[c]);
      }
    }
#pragma unroll
    for (int c = 0; c < 6; ++c) {
      float v = acc[c];
      v += __shfl_xor(v, 1);
      v += __shfl_xor(v, 2);
      v += __shfl_xor(v, 4);
      if (ks == 0) s1res[(cb1 + c) * MB + b] = v;
    }
    __syncthreads();                               // B2: s1res ready

    // ---- epilogue1: u, publish slice (system-scope stores) ----
    if (tid < MB * NS) {
      int eb = tid >> 3, n = tid & 7;
      float ap  = s1res[(0 * NS + n) * MB + eb] + xin[eb * 4 + 0] * w1r0[0 * NS + n] + b1l[0 * NS + n];
      float p1p = s1res[(1 * NS + n) * MB + eb] + xin[eb * 4 + 1] * w1r0[1 * NS + n] + b1l[1 * NS + n];
      float p2p = s1res[(2 * NS + n) * MB + eb] + xin[eb * 4 + 2] * w1r0[2 * NS + n] + b1l[2 * NS + n];
      float a  = tanhf(ap), p1 = tanhf(p1p), p2 = tanhf(p2p);
      float u  = a * p1 * p2 * (1.f - a) * (1.f - p1) * (1.f - p2);
      sys_st_f32(u_glob + (b0 + eb) * H_ + gc * NS + n, u);
    }
    vm_drain();
    __syncthreads();                               // B3: all u stores drained
    if (tid == 0) sys_st_flag(flags1 + gc, (unsigned)(t + 1));
    wait_flags(flags1, (unsigned)(t + 1), lane);

    // ---- stage u into LDS ----
    {
      f32x4 ua, ub;
      sys_ld2_x4(grp_u + tid * 4, grp_u + tid * 4 + 1024, ua, ub);
      int i0 = tid, i1 = tid + 256;
      *(f32x4*)(u_lds + (i0 >> 6) * HPAD + (i0 & 63) * 4) = ua;
      *(f32x4*)(u_lds + (i1 >> 6) * HPAD + (i1 & 63) * 4) = ub;
    }
    __syncthreads();                               // B4: u_lds ready

    // ---- stage2: z, h_cand; K=512=[u,h]; 4 cols/wave ----
    float acc2[4] = {0.f, 0.f, 0.f, 0.f};
    const int cb2 = wave * 4;
#pragma unroll
    for (int kt = 0; kt < 16; ++kt) {
      f32x4 h4 = (kt < 8) ? *(const f32x4*)(u_lds + b * HPAD + kt * 32 + ks * 4)
                          : hv[kt - 8];
#pragma unroll
      for (int c = 0; c < 4; ++c) {
        f32x4 w4 = *(const f32x4*)(w2t + (cb2 + c) * 512 + kt * 32 + ks * 4);
        acc2[c] = fmaf(h4[0], w4[0], acc2[c]);
        acc2[c] = fmaf(h4[1], w4[1], acc2[c]);
        acc2[c] = fmaf(h4[2], w4[2], acc2[c]);
        acc2[c] = fmaf(h4[3], w4[3], acc2[c]);
      }
    }
#pragma unroll
    for (int c = 0; c < 4; ++c) {
      float v = acc2[c];
      v += __shfl_xor(v, 1);
      v += __shfl_xor(v, 2);
      v += __shfl_xor(v, 4);
      if (ks == 0) s2res[(cb2 + c) * MB + b] = v;
    }
    __syncthreads();                               // B5: s2res ready

    // ---- epilogue2: h_new, publish slice ----
    if (tid < MB * NS) {
      int eb = tid >> 3, m = tid & 7;
      float zp = s2res[m * MB + eb] + bzl[m];
      float hp = s2res[(NS + m) * MB + eb] + bhl[m];
      float z  = 1.f / (1.f + expf(-zp));
      float hc = tanhf(hp);
      float hprev = h_lds[eb * HPAD + gc * NS + m];
      float hn = z * hprev + (1.f - z) * hc;
      sys_st_f32(h_glob + (b0 + eb) * H_ + gc * NS + m, hn);
      if (t == T_ - 1)
        out[B_ * T_ * 2 + (b0 + eb) * H_ + gc * NS + m] = hn;   // h_n
    }
    vm_drain();
    __syncthreads();                               // B6: all h stores drained
    if (tid == 0) sys_st_flag(flags2 + gc, (unsigned)(t + 1));
  }

  // ---- final out row (t = T-1) uses h after the last step ----
  if (gc == 0) {
    wait_flags(flags2, (unsigned)T_, lane);
    f32x4 ha, hb;
    sys_ld2_x4(grp_h + tid * 4, grp_h + tid * 4 + 1024, ha, hb);
    int i0 = tid, i1 = tid + 256;
    *(f32x4*)(h_lds + (i0 >> 6) * HPAD + (i0 & 63) * 4) = ha;
    *(f32x4*)(h_lds + (i1 >> 6) * HPAD + (i1 & 63) * 4) = hb;
    __syncthreads();
    int ob = tid >> 5, oc = tid & 31;
    const float* hr = h_lds + ob * HPAD + oc * 8;
    float v0 = 0.f, v1 = 0.f;
#pragma unroll
    for (int j = 0; j < 8; ++j) {
      float hh = hr[j];
      v0 = fmaf(hh, wo_s[(oc * 8 + j) * 2 + 0], v0);
      v1 = fmaf(hh, wo_s[(oc * 8 + j) * 2 + 1], v1);
    }
    v0 += __shfl_xor(v0, 1);  v1 += __shfl_xor(v1, 1);
    v0 += __shfl_xor(v0, 2);  v1 += __shfl_xor(v1, 2);
    v0 += __shfl_xor(v0, 4);  v1 += __shfl_xor(v1, 4);
    v0 += __shfl_xor(v0, 8);  v1 += __shfl_xor(v1, 8);
    v0 += __shfl_xor(v0, 16); v1 += __shfl_xor(v1, 16);
    if (oc == 0) {
      out[((b0 + ob) * T_ + (T_ - 1)) * 2 + 0] = v0 + bo0;
      out[((b0 + ob) * T_ + (T_ - 1)) * 2 + 1] = v1 + bo1;
    }
  }
}

extern "C" void kernel_launch(void* const* d_in, const int* in_sizes, int n_in,
                              void* d_out, int out_size, void* d_ws, size_t ws_size,
                              hipStream_t stream) {
  (void)in_sizes; (void)n_in; (void)out_size; (void)ws_size;
  const float* x   = (const float*)d_in[0];
  const float* h0  = (const float*)d_in[1];
  const float* Wa  = (const float*)d_in[2];
  const float* ba  = (const float*)d_in[3];
  const float* Wp1 = (const float*)d_in[4];
  const float* bp1 = (const float*)d_in[5];
  const float* Wp2 = (const float*)d_in[6];
  const float* bp2 = (const float*)d_in[7];
  const float* Wz  = (const float*)d_in[8];
  const float* bz  = (const float*)d_in[9];
  const float* Wh  = (const float*)d_in[10];
  const float* bh  = (const float*)d_in[11];
  const float* Wo  = (const float*)d_in[12];
  const float* bo  = (const float*)d_in[13];

  float* out = (float*)d_out;
  char*  ws  = (char*)d_ws;
  float*    u_glob = (float*)ws;                    // 131072 B
  float*    h_glob = (float*)(ws + 131072);         // 131072 B
  unsigned* ctrs   = (unsigned*)(ws + 262144);      // 4096 B of flags

  // flags must start at 0 on every replay (monotonic per-step values)
  hipMemsetAsync(ctrs, 0, 4096, stream);

  pgjanet_persist<<<dim3(GB * GC), dim3(NTHR), 0, stream>>>(
      x, h0, Wa, ba, Wp1, bp1, Wp2, bp2, Wz, bz, Wh, bh, Wo, bo,
      out, u_glob, h_glob, ctrs);
}

// Round 3
// 12961.328 us; speedup vs baseline: 4.6073x; 1.5710x over previous
//
#include <hip/hip_runtime.h>
#include <math.h>

// PGJANET persistent kernel, round 3.
// 16 batch-groups x 32 col-slice WGs. Cross-WG exchange = seq-embedded 16B
// chunks ({f,f,f,seq} dwordx4 = transaction-atomic) + per-WG flags, all via
// sc0 sc1 (coherence-point) ops. No vmcnt drains, no cache maintenance.

#define B_   128
#define T_   1024
#define H_   256
#define GB   16
#define GC   32
#define MB   8
#define NS   8
#define NTHR 256
#define HPAD 260   // LDS row stride (floats); 260%32=4 spreads banks

typedef float    f32x4 __attribute__((ext_vector_type(4)));
typedef unsigned u32x4 __attribute__((ext_vector_type(4)));

__device__ __forceinline__ void sys_st_x4(unsigned* p, u32x4 v) {
  asm volatile("global_store_dwordx4 %0, %1, off sc0 sc1" :: "v"(p), "v"(v) : "memory");
}
__device__ __forceinline__ void sys_st_u32(unsigned* p, unsigned v) {
  asm volatile("global_store_dword %0, %1, off sc0 sc1" :: "v"(p), "v"(v) : "memory");
}
__device__ __forceinline__ unsigned sys_ld_u32(const unsigned* p) {
  unsigned v;
  asm volatile("global_load_dword %0, %1, off sc0 sc1\n\ts_waitcnt vmcnt(0)"
               : "=v"(v) : "v"(p) : "memory");
  return v;
}
__device__ __forceinline__ void sys_ld3_x4(const unsigned* p, u32x4& a, u32x4& b, u32x4& c) {
  asm volatile("global_load_dwordx4 %0, %3, off sc0 sc1\n\t"
               "global_load_dwordx4 %1, %3, off offset:16 sc0 sc1\n\t"
               "global_load_dwordx4 %2, %3, off offset:32 sc0 sc1\n\t"
               "s_waitcnt vmcnt(0)"
               : "=&v"(a), "=&v"(b), "=&v"(c) : "v"(p) : "memory");
}

// wave0 polls the group's 32 per-WG flags (2 cache lines, coalesced).
__device__ __forceinline__ void poll_flags(const unsigned* fl, unsigned tgt, int lane) {
  const unsigned* p = fl + (lane & 31);
  for (;;) {
    unsigned v = tgt;
    if (lane < 32) v = sys_ld_u32(p);
    if (__ballot(v >= tgt) == ~0ull) return;
    __builtin_amdgcn_s_sleep(2);
  }
}

// lanes 0..63 hold val=v[mb=lane>>3][n=lane&7]; lanes 0..23 emit 16B chunks
// {f,f,f,seq},{f,f,f,seq},{f,f,seq,0} per mb-block (48B), 384B total per WG.
__device__ __forceinline__ void publish_block(float val, unsigned* ex_base,
                                              unsigned seq, int lane) {
  int cmb = lane / 3;
  int cpart = lane - cmb * 3;
  int sb = cmb * 8 + cpart * 3;
  float f0 = __shfl(val, sb);
  float f1 = __shfl(val, sb + 1);
  float f2 = __shfl(val, sb + 2);
  u32x4 ch;
  ch.x = __float_as_uint(f0);
  ch.y = __float_as_uint(f1);
  ch.z = (cpart == 2) ? seq : __float_as_uint(f2);
  ch.w = (cpart == 2) ? 0u  : seq;
  if (lane < 24) sys_st_x4(ex_base + lane * 4, ch);
}

// one thread consumes one (gc,mb) block: validate seqs, retry, write 8 floats to LDS.
__device__ __forceinline__ void consume_block(const unsigned* ex, unsigned seq,
                                              float* lds_row) {
  u32x4 a, b, c;
  for (;;) {
    sys_ld3_x4(ex, a, b, c);
    if (a.w == seq && b.w == seq && c.z == seq) break;
    __builtin_amdgcn_s_sleep(1);
  }
  f32x4 v0, v1;
  v0[0] = __uint_as_float(a.x); v0[1] = __uint_as_float(a.y);
  v0[2] = __uint_as_float(a.z); v0[3] = __uint_as_float(b.x);
  v1[0] = __uint_as_float(b.y); v1[1] = __uint_as_float(b.z);
  v1[2] = __uint_as_float(c.x); v1[3] = __uint_as_float(c.y);
  *(f32x4*)(lds_row)     = v0;
  *(f32x4*)(lds_row + 4) = v1;
}

__launch_bounds__(NTHR, 2)
__global__ void pgjanet_persist(
    const float* __restrict__ x,   const float* __restrict__ h0,
    const float* __restrict__ Wa,  const float* __restrict__ ba,
    const float* __restrict__ Wp1, const float* __restrict__ bp1,
    const float* __restrict__ Wp2, const float* __restrict__ bp2,
    const float* __restrict__ Wz,  const float* __restrict__ bz,
    const float* __restrict__ Wh,  const float* __restrict__ bh,
    const float* __restrict__ Wo,  const float* __restrict__ bo,
    float* __restrict__ out,        // [B*T*2] then h_n [B*H]
    unsigned* __restrict__ u_ex,    // [GB*GC*96] uints (48B per (gc,mb) block)
    unsigned* __restrict__ h_ex,    // [GB*GC*96]
    unsigned* __restrict__ ctrs)    // uflags[512], hflags[512]
{
  __shared__ __align__(16) float w1t[3 * NS * 256];   // 24 KB
  __shared__ __align__(16) float w2t[2 * NS * 512];   // 32 KB
  __shared__ __align__(16) float h_lds[MB * HPAD];    // 8.1 KB
  __shared__ __align__(16) float u_lds[MB * HPAD];    // 8.1 KB
  __shared__ float s1res[3 * NS * MB];
  __shared__ float s2res[2 * NS * MB];
  __shared__ float w1r0[3 * NS], b1l[3 * NS];
  __shared__ float bzl[NS], bhl[NS];
  __shared__ float wo_s[H_ * 2];
  __shared__ float xin[MB * 4];

  const int wg   = blockIdx.x;
  const int g    = wg >> 5;
  const int gc   = wg & (GC - 1);
  const int tid  = threadIdx.x;
  const int lane = tid & 63;
  const int wave = tid >> 6;
  const int b    = lane >> 3;
  const int ks   = lane & 7;
  const int b0   = g * MB;

  // ---- one-time weight staging (transposed to [col][k]) ----
  for (int i = tid; i < 3 * NS * 256; i += NTHR) {
    int c = i >> 8, k = i & 255;
    int mat = c >> 3, n = c & 7;
    const float* W = (mat == 0) ? Wa : (mat == 1 ? Wp1 : Wp2);
    w1t[i] = W[(1 + k) * H_ + gc * NS + n];
  }
  for (int i = tid; i < 2 * NS * 512; i += NTHR) {
    int c = i >> 9, k = i & 511;
    const float* W = (c < NS) ? Wz : Wh;
    int n = c & 7;
    w2t[i] = W[k * H_ + gc * NS + n];
  }
  if (tid < 3 * NS) {
    int mat = tid >> 3, n = tid & 7;
    const float* W  = (mat == 0) ? Wa : (mat == 1 ? Wp1 : Wp2);
    const float* bb = (mat == 0) ? ba : (mat == 1 ? bp1 : bp2);
    w1r0[tid] = W[gc * NS + n];
    b1l[tid]  = bb[gc * NS + n];
  }
  if (tid < NS) { bzl[tid] = bz[gc * NS + tid]; bhl[tid] = bh[gc * NS + tid]; }
  if (gc == 0) for (int i = tid; i < H_ * 2; i += NTHR) wo_s[i] = Wo[i];
  const float bo0 = bo[0], bo1 = bo[1];
  __syncthreads();

  unsigned* uflags_g = ctrs + g * GC;
  unsigned* hflags_g = ctrs + GB * GC + g * GC;
  unsigned* u_reg_my = u_ex + (g * GC + gc) * 96;   // this WG's publish block
  unsigned* h_reg_my = h_ex + (g * GC + gc) * 96;
  const int cgc = tid >> 3, cmb = tid & 7;          // consumer block coords
  const unsigned* u_blk = u_ex + (g * GC + cgc) * 96 + cmb * 12;
  const unsigned* h_blk = h_ex + (g * GC + cgc) * 96 + cmb * 12;
  float* lds_dst_h = h_lds + cmb * HPAD + cgc * 8;
  float* lds_dst_u = u_lds + cmb * HPAD + cgc * 8;

  for (int t = 0; t < T_; ++t) {
    // ---- x inputs (cached loads, independent of exchange) ----
    if (tid < MB) {
      float2 xt = *(const float2*)(x + (b0 + tid) * (T_ * 2) + t * 2);
      xin[tid * 4 + 0] = xt.x;
      xin[tid * 4 + 1] = cosf(xt.y);
      xin[tid * 4 + 2] = sinf(xt.y);
    }
    // ---- acquire h(t) ----
    if (t == 0) {
      const float* h0g = h0 + b0 * H_;
      f32x4 ha = *(const f32x4*)(h0g + tid * 4);
      f32x4 hb = *(const f32x4*)(h0g + tid * 4 + 1024);
      *(f32x4*)(h_lds + (tid >> 6) * HPAD + (tid & 63) * 4) = ha;
      *(f32x4*)(h_lds + ((tid + 256) >> 6) * HPAD + (tid & 63) * 4) = hb;
    } else {
      if (wave == 0) poll_flags(hflags_g, (unsigned)t, lane);
      __syncthreads();
      consume_block(h_blk, (unsigned)t, lds_dst_h);
    }
    __syncthreads();                               // h_lds, xin ready

    // ---- stage1: h-part of a,p1,p2 pre-acts (6 cols/wave) ----
    f32x4 hv[8];
#pragma unroll
    for (int kt = 0; kt < 8; ++kt)
      hv[kt] = *(const f32x4*)(h_lds + b * HPAD + kt * 32 + ks * 4);

    float acc[6] = {0.f, 0.f, 0.f, 0.f, 0.f, 0.f};
    const int cb1 = wave * 6;
#pragma unroll
    for (int kt = 0; kt < 8; ++kt) {
      f32x4 h4 = hv[kt];
#pragma unroll
      for (int c = 0; c < 6; ++c) {
        f32x4 w4 = *(const f32x4*)(w1t + (cb1 + c) * 256 + kt * 32 + ks * 4);
        acc[c] = fmaf(h4[0], w4[0], acc[c]);
        acc[c] = fmaf(h4[1], w4[1], acc[c]);
        acc[c] = fmaf(h4[2], w4[2], acc[c]);
        acc[c] = fmaf(h4[3], w4[3], acc[c]);
      }
    }
#pragma unroll
    for (int c = 0; c < 6; ++c) {
      float v = acc[c];
      v += __shfl_xor(v, 1);
      v += __shfl_xor(v, 2);
      v += __shfl_xor(v, 4);
      if (ks == 0) s1res[(cb1 + c) * MB + b] = v;
    }
    __syncthreads();                               // s1res ready

    // ---- epilogue1 (wave0): u, publish chunks + flag (no drain) ----
    if (tid < 64) {
      int eb = tid >> 3, n = tid & 7;
      float ap  = s1res[(0 * NS + n) * MB + eb] + xin[eb * 4 + 0] * w1r0[0 * NS + n] + b1l[0 * NS + n];
      float p1p = s1res[(1 * NS + n) * MB + eb] + xin[eb * 4 + 1] * w1r0[1 * NS + n] + b1l[1 * NS + n];
      float p2p = s1res[(2 * NS + n) * MB + eb] + xin[eb * 4 + 2] * w1r0[2 * NS + n] + b1l[2 * NS + n];
      float a  = tanhf(ap), p1 = tanhf(p1p), p2 = tanhf(p2p);
      float u  = a * p1 * p2 * (1.f - a) * (1.f - p1) * (1.f - p2);
      publish_block(u, u_reg_my, (unsigned)(t + 1), lane);
      if (tid == 0) sys_st_u32(uflags_g + gc, (unsigned)(t + 1));
    }

    // ---- gc0: fused out-row for t-1 (hidden in the u-wait window) ----
    if (gc == 0 && t > 0) {
      int ob = tid >> 5, oc = tid & 31;
      const float* hr = h_lds + ob * HPAD + oc * 8;
      float v0 = 0.f, v1 = 0.f;
#pragma unroll
      for (int j = 0; j < 8; ++j) {
        float hh = hr[j];
        v0 = fmaf(hh, wo_s[(oc * 8 + j) * 2 + 0], v0);
        v1 = fmaf(hh, wo_s[(oc * 8 + j) * 2 + 1], v1);
      }
      v0 += __shfl_xor(v0, 1);  v1 += __shfl_xor(v1, 1);
      v0 += __shfl_xor(v0, 2);  v1 += __shfl_xor(v1, 2);
      v0 += __shfl_xor(v0, 4);  v1 += __shfl_xor(v1, 4);
      v0 += __shfl_xor(v0, 8);  v1 += __shfl_xor(v1, 8);
      v0 += __shfl_xor(v0, 16); v1 += __shfl_xor(v1, 16);
      if (oc == 0) {
        out[((b0 + ob) * T_ + (t - 1)) * 2 + 0] = v0 + bo0;
        out[((b0 + ob) * T_ + (t - 1)) * 2 + 1] = v1 + bo1;
      }
    }

    // ---- stage2 h-part (registers only; overlaps the u exchange) ----
    float acc2[4] = {0.f, 0.f, 0.f, 0.f};
    const int cb2 = wave * 4;
#pragma unroll
    for (int kt = 0; kt < 8; ++kt) {
      f32x4 h4 = hv[kt];
#pragma unroll
      for (int c = 0; c < 4; ++c) {
        f32x4 w4 = *(const f32x4*)(w2t + (cb2 + c) * 512 + (8 + kt) * 32 + ks * 4);
        acc2[c] = fmaf(h4[0], w4[0], acc2[c]);
        acc2[c] = fmaf(h4[1], w4[1], acc2[c]);
        acc2[c] = fmaf(h4[2], w4[2], acc2[c]);
        acc2[c] = fmaf(h4[3], w4[3], acc2[c]);
      }
    }

    // ---- acquire u(t) ----
    if (wave == 0) poll_flags(uflags_g, (unsigned)(t + 1), lane);
    __syncthreads();
    consume_block(u_blk, (unsigned)(t + 1), lds_dst_u);
    __syncthreads();                               // u_lds ready

    // ---- stage2 u-part ----
#pragma unroll
    for (int kt = 0; kt < 8; ++kt) {
      f32x4 u4 = *(const f32x4*)(u_lds + b * HPAD + kt * 32 + ks * 4);
#pragma unroll
      for (int c = 0; c < 4; ++c) {
        f32x4 w4 = *(const f32x4*)(w2t + (cb2 + c) * 512 + kt * 32 + ks * 4);
        acc2[c] = fmaf(u4[0], w4[0], acc2[c]);
        acc2[c] = fmaf(u4[1], w4[1], acc2[c]);
        acc2[c] = fmaf(u4[2], w4[2], acc2[c]);
        acc2[c] = fmaf(u4[3], w4[3], acc2[c]);
      }
    }
#pragma unroll
    for (int c = 0; c < 4; ++c) {
      float v = acc2[c];
      v += __shfl_xor(v, 1);
      v += __shfl_xor(v, 2);
      v += __shfl_xor(v, 4);
      if (ks == 0) s2res[(cb2 + c) * MB + b] = v;
    }
    __syncthreads();                               // s2res ready

    // ---- epilogue2 (wave0): h_new, publish chunks + flag ----
    if (tid < 64) {
      int eb = tid >> 3, m = tid & 7;
      float zp = s2res[m * MB + eb] + bzl[m];
      float hp = s2res[(NS + m) * MB + eb] + bhl[m];
      float z  = 1.f / (1.f + expf(-zp));
      float hc = tanhf(hp);
      float hprev = h_lds[eb * HPAD + gc * NS + m];
      float hn = z * hprev + (1.f - z) * hc;
      publish_block(hn, h_reg_my, (unsigned)(t + 1), lane);
      if (tid == 0) sys_st_u32(hflags_g + gc, (unsigned)(t + 1));
      if (t == T_ - 1)
        out[B_ * T_ * 2 + (b0 + eb) * H_ + gc * NS + m] = hn;   // h_n
    }
  }

  // ---- final out row (t = T-1) from h(T) ----
  if (gc == 0) {
    if (wave == 0) poll_flags(hflags_g, (unsigned)T_, lane);
    __syncthreads();
    consume_block(h_blk, (unsigned)T_, lds_dst_h);
    __syncthreads();
    int ob = tid >> 5, oc = tid & 31;
    const float* hr = h_lds + ob * HPAD + oc * 8;
    float v0 = 0.f, v1 = 0.f;
#pragma unroll
    for (int j = 0; j < 8; ++j) {
      float hh = hr[j];
      v0 = fmaf(hh, wo_s[(oc * 8 + j) * 2 + 0], v0);
      v1 = fmaf(hh, wo_s[(oc * 8 + j) * 2 + 1], v1);
    }
    v0 += __shfl_xor(v0, 1);  v1 += __shfl_xor(v1, 1);
    v0 += __shfl_xor(v0, 2);  v1 += __shfl_xor(v1, 2);
    v0 += __shfl_xor(v0, 4);  v1 += __shfl_xor(v1, 4);
    v0 += __shfl_xor(v0, 8);  v1 += __shfl_xor(v1, 8);
    v0 += __shfl_xor(v0, 16); v1 += __shfl_xor(v1, 16);
    if (oc == 0) {
      out[((b0 + ob) * T_ + (T_ - 1)) * 2 + 0] = v0 + bo0;
      out[((b0 + ob) * T_ + (T_ - 1)) * 2 + 1] = v1 + bo1;
    }
  }
}

extern "C" void kernel_launch(void* const* d_in, const int* in_sizes, int n_in,
                              void* d_out, int out_size, void* d_ws, size_t ws_size,
                              hipStream_t stream) {
  (void)in_sizes; (void)n_in; (void)out_size; (void)ws_size;
  const float* x   = (const float*)d_in[0];
  const float* h0  = (const float*)d_in[1];
  const float* Wa  = (const float*)d_in[2];
  const float* ba  = (const float*)d_in[3];
  const float* Wp1 = (const float*)d_in[4];
  const float* bp1 = (const float*)d_in[5];
  const float* Wp2 = (const float*)d_in[6];
  const float* bp2 = (const float*)d_in[7];
  const float* Wz  = (const float*)d_in[8];
  const float* bz  = (const float*)d_in[9];
  const float* Wh  = (const float*)d_in[10];
  const float* bh  = (const float*)d_in[11];
  const float* Wo  = (const float*)d_in[12];
  const float* bo  = (const float*)d_in[13];

  float* out = (float*)d_out;
  char*  ws  = (char*)d_ws;
  unsigned* u_ex = (unsigned*)ws;                         // 16*32*96*4 = 196608 B
  unsigned* h_ex = (unsigned*)(ws + 196608);              // 196608 B
  unsigned* ctrs = (unsigned*)(ws + 393216);              // 4096 B flags

  // flags must start at 0 each replay (seq values are per-run monotonic;
  // data chunks are gated by flags + equality-checked embedded seqs).
  hipMemsetAsync(ctrs, 0, 4096, stream);

  pgjanet_persist<<<dim3(GB * GC), dim3(NTHR), 0, stream>>>(
      x, h0, Wa, ba, Wp1, bp1, Wp2, bp2, Wz, bz, Wh, bh, Wo, bo,
      out, u_ex, h_ex, ctrs);
}

// Round 4
// 5697.908 us; speedup vs baseline: 10.4805x; 2.2748x over previous
//
#include <hip/hip_runtime.h>
#include <math.h>

// PGJANET persistent kernel, round 4.
// 16 batch-groups x 16 col-slice WGs (512 thr, 1 WG/CU). Cross-WG exchange:
// self-validating 16B chunks {f0,f1,seq,0} via sc0 sc1 dwordx4 (transaction-
// atomic). Consumers poll the data directly -- no flags, no drains, 1 IC hop
// per exchange. Per-wave publish (no barrier between compute and publish).

#define B_   128
#define T_   1024
#define H_   256
#define GB   16
#define GC   16
#define MB   8
#define NS   16
#define NTHR 512
#define HPAD 264   // 264%32==8 -> 2-way LDS aliasing (free)

typedef float    f32x4 __attribute__((ext_vector_type(4)));
typedef unsigned u32x4 __attribute__((ext_vector_type(4)));

__device__ __forceinline__ void sys_st_x4(unsigned* p, u32x4 v) {
  asm volatile("global_store_dwordx4 %0, %1, off sc0 sc1" :: "v"(p), "v"(v) : "memory");
}
__device__ __forceinline__ void sys_ld2_x4(const unsigned* p0, const unsigned* p1,
                                           u32x4& a, u32x4& b) {
  asm volatile("global_load_dwordx4 %0, %2, off sc0 sc1\n\t"
               "global_load_dwordx4 %1, %3, off sc0 sc1\n\t"
               "s_waitcnt vmcnt(0)"
               : "=&v"(a), "=&v"(b) : "v"(p0), "v"(p1) : "memory");
}

__launch_bounds__(NTHR, 1)
__global__ void pgjanet_persist(
    const float* __restrict__ x,   const float* __restrict__ h0,
    const float* __restrict__ Wa,  const float* __restrict__ ba,
    const float* __restrict__ Wp1, const float* __restrict__ bp1,
    const float* __restrict__ Wp2, const float* __restrict__ bp2,
    const float* __restrict__ Wz,  const float* __restrict__ bz,
    const float* __restrict__ Wh,  const float* __restrict__ bh,
    const float* __restrict__ Wo,  const float* __restrict__ bo,
    float* __restrict__ out,        // [B*T*2] then h_n [B*H]
    unsigned* __restrict__ u_ex,    // [GB][1024] 16B chunks
    unsigned* __restrict__ h_ex)    // [GB][1024]
{
  __shared__ __align__(16) float w1t[3 * NS * 256];   // 48 KB  [mat*16+n][k]
  __shared__ __align__(16) float w2t[2 * NS * 512];   // 64 KB  [mat*16+n][k] k<256:u, k>=256:h
  __shared__ __align__(16) float h_lds[MB * HPAD];    // 8.25 KB
  __shared__ __align__(16) float u_lds[MB * HPAD];    // 8.25 KB
  __shared__ __align__(16) float wo_s[H_ * 2];        // 2 KB
  __shared__ __align__(16) float xin[2 * MB * 4];     // double-buffered {amp,cos,sin,0}

  const int wg   = blockIdx.x;
  const int g    = wg >> 4;
  const int gc   = wg & (GC - 1);
  const int tid  = threadIdx.x;
  const int lane = tid & 63;
  const int wave = tid >> 6;       // 0..7, owns cols {2w, 2w+1}
  const int mb   = lane >> 3;      // batch 0..7
  const int ks   = lane & 7;       // k-chunk lane
  const int b0   = g * MB;
  const int n0   = gc * NS + wave * 2;   // global col of this wave's col 0

  // ---- one-time weight staging ----
  for (int i = tid; i < 3 * NS * 256; i += NTHR) {
    int c = i >> 8, k = i & 255;
    int mat = c >> 4, n = c & 15;
    const float* W = (mat == 0) ? Wa : (mat == 1 ? Wp1 : Wp2);
    w1t[i] = W[(1 + k) * H_ + gc * NS + n];
  }
  for (int i = tid; i < 2 * NS * 512; i += NTHR) {
    int c = i >> 9, k = i & 511;
    int mat = c >> 4, n = c & 15;
    const float* W = (mat == 0) ? Wz : Wh;
    w2t[i] = W[k * H_ + gc * NS + n];
  }
  for (int i = tid; i < H_ * 2; i += NTHR) wo_s[i] = Wo[i];

  // per-thread weight-invariants (wave-uniform)
  float w1r0_[6], b1_[6];
#pragma unroll
  for (int m = 0; m < 3; ++m) {
    const float* W  = (m == 0) ? Wa : (m == 1 ? Wp1 : Wp2);
    const float* bb = (m == 0) ? ba : (m == 1 ? bp1 : bp2);
#pragma unroll
    for (int cc = 0; cc < 2; ++cc) {
      w1r0_[m * 2 + cc] = W[n0 + cc];
      b1_[m * 2 + cc]   = bb[n0 + cc];
    }
  }
  float bz_[2] = { bz[n0], bz[n0 + 1] };
  float bh_[2] = { bh[n0], bh[n0 + 1] };
  const float bo0 = bo[0], bo1 = bo[1];

  // h0 -> h_lds ; x(0) -> xin[0]
  {
    int flat = tid * 4;                 // 0..2047
    int mbb = flat >> 8, kk = flat & 255;
    *(f32x4*)(h_lds + mbb * HPAD + kk) = *(const f32x4*)(h0 + (b0 + mbb) * H_ + kk);
  }
  if (tid < MB) {
    float2 xt = *(const float2*)(x + ((b0 + tid) * T_) * 2);
    f32x4 xi; xi[0] = xt.x; xi[1] = cosf(xt.y); xi[2] = sinf(xt.y); xi[3] = 0.f;
    *(f32x4*)(xin + tid * 4) = xi;
  }
  __syncthreads();

  unsigned* u_exg = u_ex + g * 4096;    // 1024 chunks * 4 uints
  unsigned* h_exg = h_ex + g * 4096;
  unsigned* u_my  = u_exg + ((gc * 8 + wave) * 8) * 4;   // + mb*4
  unsigned* h_my  = h_exg + ((gc * 8 + wave) * 8) * 4;

  for (int t = 0; t < T_; ++t) {
    const unsigned seq = (unsigned)(t + 1);

    // ---- stage1 GEMV: 3 mats x 2 cols over K=256 (h in regs) ----
    f32x4 hv[8];
#pragma unroll
    for (int kt = 0; kt < 8; ++kt)
      hv[kt] = *(const f32x4*)(h_lds + mb * HPAD + kt * 32 + ks * 4);

    float acc[6] = {0.f, 0.f, 0.f, 0.f, 0.f, 0.f};
#pragma unroll
    for (int kt = 0; kt < 8; ++kt) {
      f32x4 h4 = hv[kt];
#pragma unroll
      for (int m = 0; m < 3; ++m)
#pragma unroll
        for (int cc = 0; cc < 2; ++cc) {
          f32x4 w4 = *(const f32x4*)(w1t + (m * NS + wave * 2 + cc) * 256 + kt * 32 + ks * 4);
          float s = acc[m * 2 + cc];
          s = fmaf(h4[0], w4[0], s); s = fmaf(h4[1], w4[1], s);
          s = fmaf(h4[2], w4[2], s); s = fmaf(h4[3], w4[3], s);
          acc[m * 2 + cc] = s;
        }
    }
#pragma unroll
    for (int i = 0; i < 6; ++i) {
      float v = acc[i];
      v += __shfl_xor(v, 1);
      v += __shfl_xor(v, 2);
      v += __shfl_xor(v, 4);
      acc[i] = v;
    }
    // ---- epilogue1 + immediate per-wave publish (lanes ks==0) ----
    if (ks == 0) {
      f32x4 xi = *(const f32x4*)(xin + ((t & 1) * MB + mb) * 4);
      float uu[2];
#pragma unroll
      for (int cc = 0; cc < 2; ++cc) {
        float a  = tanhf(acc[0 + cc] + xi[0] * w1r0_[0 + cc] + b1_[0 + cc]);
        float p1 = tanhf(acc[2 + cc] + xi[1] * w1r0_[2 + cc] + b1_[2 + cc]);
        float p2 = tanhf(acc[4 + cc] + xi[2] * w1r0_[4 + cc] + b1_[4 + cc]);
        uu[cc] = a * p1 * p2 * (1.f - a) * (1.f - p1) * (1.f - p2);
      }
      u32x4 ch;
      ch.x = __float_as_uint(uu[0]); ch.y = __float_as_uint(uu[1]);
      ch.z = seq; ch.w = 0u;
      sys_st_x4(u_my + mb * 4, ch);
    }

    // ---- latency window: x prefetch, out-row GEMV, stage2 h-part ----
    if (t + 1 < T_ && tid < MB) {
      float2 xt = *(const float2*)(x + ((b0 + tid) * T_ + (t + 1)) * 2);
      f32x4 xi; xi[0] = xt.x; xi[1] = cosf(xt.y); xi[2] = sinf(xt.y); xi[3] = 0.f;
      *(f32x4*)(xin + (((t + 1) & 1) * MB + tid) * 4) = xi;
    }
    if (t > 0 && ((t - 1) & 15) == gc) {
      // out[t-1] = h(t) @ Wo + bo ; wave w handles batch w
      f32x4 h4  = *(const f32x4*)(h_lds + wave * HPAD + lane * 4);
      f32x4 wo0 = *(const f32x4*)(wo_s + lane * 8);
      f32x4 wo1 = *(const f32x4*)(wo_s + lane * 8 + 4);
      float v0 = h4[0] * wo0[0] + h4[1] * wo0[2] + h4[2] * wo1[0] + h4[3] * wo1[2];
      float v1 = h4[0] * wo0[1] + h4[1] * wo0[3] + h4[2] * wo1[1] + h4[3] * wo1[3];
      v0 += __shfl_xor(v0, 1);  v1 += __shfl_xor(v1, 1);
      v0 += __shfl_xor(v0, 2);  v1 += __shfl_xor(v1, 2);
      v0 += __shfl_xor(v0, 4);  v1 += __shfl_xor(v1, 4);
      v0 += __shfl_xor(v0, 8);  v1 += __shfl_xor(v1, 8);
      v0 += __shfl_xor(v0, 16); v1 += __shfl_xor(v1, 16);
      v0 += __shfl_xor(v0, 32); v1 += __shfl_xor(v1, 32);
      if (lane == 0) {
        float2 o; o.x = v0 + bo0; o.y = v1 + bo1;
        *(float2*)(out + ((b0 + wave) * T_ + (t - 1)) * 2) = o;
      }
    }
    float acc2[4] = {0.f, 0.f, 0.f, 0.f};
#pragma unroll
    for (int kt = 0; kt < 8; ++kt) {
      f32x4 h4 = hv[kt];
#pragma unroll
      for (int m = 0; m < 2; ++m)
#pragma unroll
        for (int cc = 0; cc < 2; ++cc) {
          f32x4 w4 = *(const f32x4*)(w2t + (m * NS + wave * 2 + cc) * 512 + 256 + kt * 32 + ks * 4);
          float s = acc2[m * 2 + cc];
          s = fmaf(h4[0], w4[0], s); s = fmaf(h4[1], w4[1], s);
          s = fmaf(h4[2], w4[2], s); s = fmaf(h4[3], w4[3], s);
          acc2[m * 2 + cc] = s;
        }
    }

    // ---- consume u: poll own 2 chunks, write LDS ----
    {
      u32x4 A, B;
      const unsigned* p0 = u_exg + tid * 4;
      const unsigned* p1 = u_exg + (tid + 512) * 4;
      for (;;) {
        sys_ld2_x4(p0, p1, A, B);
        if (A.z == seq && B.z == seq) break;
        __builtin_amdgcn_s_sleep(1);
      }
      int c = tid;
      float2 d0; d0.x = __uint_as_float(A.x); d0.y = __uint_as_float(A.y);
      *(float2*)(u_lds + (c & 7) * HPAD + (c >> 6) * 16 + ((c >> 3) & 7) * 2) = d0;
      c = tid + 512;
      float2 d1; d1.x = __uint_as_float(B.x); d1.y = __uint_as_float(B.y);
      *(float2*)(u_lds + (c & 7) * HPAD + (c >> 6) * 16 + ((c >> 3) & 7) * 2) = d1;
    }
    __syncthreads();                        // u_lds ready

    // ---- stage2 u-part ----
#pragma unroll
    for (int kt = 0; kt < 8; ++kt) {
      f32x4 u4 = *(const f32x4*)(u_lds + mb * HPAD + kt * 32 + ks * 4);
#pragma unroll
      for (int m = 0; m < 2; ++m)
#pragma unroll
        for (int cc = 0; cc < 2; ++cc) {
          f32x4 w4 = *(const f32x4*)(w2t + (m * NS + wave * 2 + cc) * 512 + kt * 32 + ks * 4);
          float s = acc2[m * 2 + cc];
          s = fmaf(u4[0], w4[0], s); s = fmaf(u4[1], w4[1], s);
          s = fmaf(u4[2], w4[2], s); s = fmaf(u4[3], w4[3], s);
          acc2[m * 2 + cc] = s;
        }
    }
#pragma unroll
    for (int i = 0; i < 4; ++i) {
      float v = acc2[i];
      v += __shfl_xor(v, 1);
      v += __shfl_xor(v, 2);
      v += __shfl_xor(v, 4);
      acc2[i] = v;
    }
    // ---- epilogue2 + per-wave publish h_new ----
    if (ks == 0) {
      float z0  = 1.f / (1.f + expf(-(acc2[0] + bz_[0])));
      float z1  = 1.f / (1.f + expf(-(acc2[1] + bz_[1])));
      float hc0 = tanhf(acc2[2] + bh_[0]);
      float hc1 = tanhf(acc2[3] + bh_[1]);
      float2 hp = *(const float2*)(h_lds + mb * HPAD + n0);
      float hn0 = z0 * hp.x + (1.f - z0) * hc0;
      float hn1 = z1 * hp.y + (1.f - z1) * hc1;
      u32x4 ch;
      ch.x = __float_as_uint(hn0); ch.y = __float_as_uint(hn1);
      ch.z = seq; ch.w = 0u;
      sys_st_x4(h_my + mb * 4, ch);
      if (t == T_ - 1) {
        float2 o; o.x = hn0; o.y = hn1;
        *(float2*)(out + B_ * T_ * 2 + (b0 + mb) * H_ + n0) = o;
      }
    }
    __syncthreads();   // all epilogue2 h_lds(hprev) reads done before overwrite

    // ---- consume h -> h_lds ----
    {
      u32x4 A, B;
      const unsigned* p0 = h_exg + tid * 4;
      const unsigned* p1 = h_exg + (tid + 512) * 4;
      for (;;) {
        sys_ld2_x4(p0, p1, A, B);
        if (A.z == seq && B.z == seq) break;
        __builtin_amdgcn_s_sleep(1);
      }
      int c = tid;
      float2 d0; d0.x = __uint_as_float(A.x); d0.y = __uint_as_float(A.y);
      *(float2*)(h_lds + (c & 7) * HPAD + (c >> 6) * 16 + ((c >> 3) & 7) * 2) = d0;
      c = tid + 512;
      float2 d1; d1.x = __uint_as_float(B.x); d1.y = __uint_as_float(B.y);
      *(float2*)(h_lds + (c & 7) * HPAD + (c >> 6) * 16 + ((c >> 3) & 7) * 2) = d1;
    }
    __syncthreads();                        // h(t+1) ready
  }

  // ---- tail: out[T-1] from h(T) (already in h_lds) ----
  if (gc == ((T_ - 1) & 15)) {
    f32x4 h4  = *(const f32x4*)(h_lds + wave * HPAD + lane * 4);
    f32x4 wo0 = *(const f32x4*)(wo_s + lane * 8);
    f32x4 wo1 = *(const f32x4*)(wo_s + lane * 8 + 4);
    float v0 = h4[0] * wo0[0] + h4[1] * wo0[2] + h4[2] * wo1[0] + h4[3] * wo1[2];
    float v1 = h4[0] * wo0[1] + h4[1] * wo0[3] + h4[2] * wo1[1] + h4[3] * wo1[3];
    v0 += __shfl_xor(v0, 1);  v1 += __shfl_xor(v1, 1);
    v0 += __shfl_xor(v0, 2);  v1 += __shfl_xor(v1, 2);
    v0 += __shfl_xor(v0, 4);  v1 += __shfl_xor(v1, 4);
    v0 += __shfl_xor(v0, 8);  v1 += __shfl_xor(v1, 8);
    v0 += __shfl_xor(v0, 16); v1 += __shfl_xor(v1, 16);
    v0 += __shfl_xor(v0, 32); v1 += __shfl_xor(v1, 32);
    if (lane == 0) {
      float2 o; o.x = v0 + bo0; o.y = v1 + bo1;
      *(float2*)(out + ((b0 + wave) * T_ + (T_ - 1)) * 2) = o;
    }
  }
}

extern "C" void kernel_launch(void* const* d_in, const int* in_sizes, int n_in,
                              void* d_out, int out_size, void* d_ws, size_t ws_size,
                              hipStream_t stream) {
  (void)in_sizes; (void)n_in; (void)out_size; (void)ws_size;
  const float* x   = (const float*)d_in[0];
  const float* h0  = (const float*)d_in[1];
  const float* Wa  = (const float*)d_in[2];
  const float* ba  = (const float*)d_in[3];
  const float* Wp1 = (const float*)d_in[4];
  const float* bp1 = (const float*)d_in[5];
  const float* Wp2 = (const float*)d_in[6];
  const float* bp2 = (const float*)d_in[7];
  const float* Wz  = (const float*)d_in[8];
  const float* bz  = (const float*)d_in[9];
  const float* Wh  = (const float*)d_in[10];
  const float* bh  = (const float*)d_in[11];
  const float* Wo  = (const float*)d_in[12];
  const float* bo  = (const float*)d_in[13];

  float* out = (float*)d_out;
  char*  ws  = (char*)d_ws;
  unsigned* u_ex = (unsigned*)ws;                 // 16 groups * 16KB = 256 KB
  unsigned* h_ex = (unsigned*)(ws + 262144);      // 256 KB

  // seqs restart at 1 every replay -> stale chunks from a previous replay
  // would carry valid-looking seqs. Zero both exchange regions each launch.
  hipMemsetAsync(ws, 0, 524288, stream);

  pgjanet_persist<<<dim3(GB * GC), dim3(NTHR), 0, stream>>>(
      x, h0, Wa, ba, Wp1, bp1, Wp2, bp2, Wz, bz, Wh, bh, Wo, bo,
      out, u_ex, h_ex);
}